// Round 5
// baseline (206.399 us; speedup 1.0000x reference)
//
#include <hip/hip_runtime.h>

#define PH 7
#define PW 7
#define NB 49
#define SSCALE 0.0625f
#define CC 256
#define HH 200
#define WW 200
#define HWSZ (HH * WW)

#define CPW 16            // channels per wave
#define TDIM 41           // tile dim incl. +1 duplicated edge row/col (footprint <= 40)
#define TSZ (TDIM * TDIM) // 1681 floats per wave slice (6724 B)

__global__ __launch_bounds__(256) void roi_align_v5(
    const float* __restrict__ features, const float* __restrict__ rois,
    float* __restrict__ out)
{
    __shared__ float tile4[4 * TSZ];    // 26.9 KB, one private slice per wave

    const int n    = blockIdx.x;                 // roi
    const int wid  = threadIdx.x >> 6;           // wave in block 0..3
    const int lane = threadIdx.x & 63;
    const int c0   = (blockIdx.y * 4 + wid) * CPW;  // first channel of this wave
    float* tile = &tile4[wid * TSZ];

    // ---- roi params (uniform within wave; broadcast loads) ----
    const float* r = rois + (size_t)n * 5;
    const int   b  = (int)r[0];
    const float x1 = r[1] * SSCALE, y1 = r[2] * SSCALE;
    const float x2 = r[3] * SSCALE, y2 = r[4] * SSCALE;
    const float bw = fmaxf(x2 - x1, 1.f) * (1.f / PW);
    const float bh = fmaxf(y2 - y1, 1.f) * (1.f / PH);

    // footprint: samples at y1 + [0.25..6.75]*bh
    const float yA = y1 + 0.25f * bh, yB = y1 + 6.75f * bh;
    const float xA = x1 + 0.25f * bw, xB = x1 + 6.75f * bw;
    const int row0 = min((int)fmaxf(yA, 0.f), HH - 1);
    const int rowL = min((int)fmaxf(yB, 0.f), HH - 1);
    const int th   = min(rowL + 1, HH - 1) - row0 + 1;      // real rows <= 40
    const int col0 = min((int)fmaxf(xA, 0.f), WW - 1);
    const int colL = min((int)fmaxf(xB, 0.f), WW - 1);
    const int tw   = min(colL + 1, WW - 1) - col0 + 1;      // real cols <= 40

    const int   ecols = tw + 1;               // staged cols incl. dup edge
    const int   nelem = (th + 1) * ecols;     // staged elements incl. dup row
    const float rcpc  = 1.0f / (float)ecols;  // once per wave; IEEE div

    // ---- per-lane bin weights & LDS offsets: computed ONCE per wave ----
    const int bin = (lane < NB) ? lane : NB - 1;
    const int ph  = bin / PW;
    const int pw  = bin - ph * PW;

    int   oy[2], ox[2];
    float wy0[2], wy1[2], wx0[2], wx1[2];
    #pragma unroll
    for (int i = 0; i < 2; ++i) {
        float sf = i ? 0.75f : 0.25f;

        float y  = y1 + ((float)ph + sf) * bh;
        bool  vy = (y >= -1.f) && (y <= (float)HH);
        float cy = fmaxf(y, 0.f);
        int   yl = min((int)cy, HH - 1);
        float fy = (yl >= HH - 1) ? 0.f : (cy - (float)yl);
        wy0[i] = vy ? (1.f - fy) : 0.f;
        wy1[i] = vy ? fy : 0.f;
        oy[i]  = (yl - row0) * TDIM;

        float x  = x1 + ((float)pw + sf) * bw;
        bool  vx = (x >= -1.f) && (x <= (float)WW);
        float cx = fmaxf(x, 0.f);
        int   xl = min((int)cx, WW - 1);
        float fx = (xl >= WW - 1) ? 0.f : (cx - (float)xl);
        wx0[i] = vx ? (1.f - fx) : 0.f;
        wx1[i] = vx ? fx : 0.f;
        ox[i]  = xl - col0;
    }
    // 16 tap-weight products (validity already folded in)
    float w00[4], w01[4], w10[4], w11[4];
    int   ob[4];
    #pragma unroll
    for (int iy = 0; iy < 2; ++iy)
        #pragma unroll
        for (int ix = 0; ix < 2; ++ix) {
            int s = iy * 2 + ix;
            w00[s] = wy0[iy] * wx0[ix];
            w01[s] = wy0[iy] * wx1[ix];
            w10[s] = wy1[iy] * wx0[ix];
            w11[s] = wy1[iy] * wx1[ix];
            ob[s]  = oy[iy] + ox[ix];
        }

    const float* fb = features + ((size_t)b * CC + c0) * HWSZ
                    + (size_t)row0 * WW + col0;
    float* ob_out = out + ((size_t)n * CC + c0) * NB;

    for (int ch = 0; ch < CPW; ++ch) {
        const float* fp = fb + (size_t)ch * HWSZ;

        // ---- stage footprint (+dup edge) : wave-local, no barrier ----
        for (int e = lane; e < nelem; e += 64) {
            int rr = (int)(((float)e + 0.5f) * rcpc);   // exact floor(e/ecols)
            int cc = e - rr * ecols;
            int rs = min(rr, th - 1);                   // dup last row
            int cs = min(cc, tw - 1);                   // dup last col
            tile[rr * TDIM + cc] = fp[rs * WW + cs];
        }
        // compiler inserts lgkmcnt wait on the aliasing LDS read below;
        // only this wave touches `tile`, so no __syncthreads needed.

        // ---- compute 49 bins from LDS ----
        float acc = 0.f;
        #pragma unroll
        for (int s = 0; s < 4; ++s) {
            const float* p = tile + ob[s];
            float v00 = p[0];
            float v01 = p[1];          // dup-edge guarantees in-slice, finite
            float v10 = p[TDIM];
            float v11 = p[TDIM + 1];
            acc += w00[s] * v00 + w01[s] * v01 + w10[s] * v10 + w11[s] * v11;
        }
        if (lane < NB)
            ob_out[(size_t)ch * NB + lane] = acc * 0.25f;
    }
}

extern "C" void kernel_launch(void* const* d_in, const int* in_sizes, int n_in,
                              void* d_out, int out_size, void* d_ws, size_t ws_size,
                              hipStream_t stream) {
    const float* features = (const float*)d_in[0];
    const float* rois     = (const float*)d_in[1];
    float*       out      = (float*)d_out;

    int N = in_sizes[1] / 5;   // 512 rois

    dim3 grid(N, 4);           // 512 x 4 blocks; 4 waves/block x 16 ch = 256 ch
    roi_align_v5<<<grid, 256, 0, stream>>>(features, rois, out);
}